// Round 7
// baseline (583.345 us; speedup 1.0000x reference)
//
#include <hip/hip_runtime.h>
#include <math.h>

// Problem constants
#define B_ 4
#define T_ 2048
#define E_ 1024
#define H_ 16
#define HS_ 64
#define FF_ 4096
#define M_ (B_ * T_)          // 8192 rows
#define QKV3_ (3 * H_ * HS_)  // 3072

typedef short bf16x8 __attribute__((ext_vector_type(8)));
typedef short bf16x4 __attribute__((ext_vector_type(4)));
typedef float f32x4 __attribute__((ext_vector_type(4)));

// fp32 -> bf16 (round-to-nearest-even), bit ops only
__device__ __forceinline__ unsigned short f2bf(float f) {
    unsigned int u = __float_as_uint(f);
    return (unsigned short)((u + 0x7fffu + ((u >> 16) & 1u)) >> 16);
}

// async global->LDS, 16B per lane (wave-uniform LDS base + lane*16)
__device__ __forceinline__ void gload16(const void* g, void* l) {
    __builtin_amdgcn_global_load_lds(
        (const __attribute__((address_space(1))) void*)g,
        (__attribute__((address_space(3))) void*)l, 16, 0, 0);
}

// ---------------------------------------------------------------------------
// Weight transpose + cast: W[K][N] fp32 -> WT[N][K] bf16. 32x32 tiles.
// ---------------------------------------------------------------------------
__global__ __launch_bounds__(256) void wT_bf16(const float* __restrict__ W,
                                               unsigned short* __restrict__ WT,
                                               int K, int N) {
    __shared__ float t[32][33];
    const int n0 = blockIdx.x * 32, k0 = blockIdx.y * 32;
    const int tid = threadIdx.x;
#pragma unroll
    for (int i = 0; i < 4; i++) {
        const int idx = i * 256 + tid;
        const int r = idx >> 5, c = idx & 31;
        t[r][c] = W[(size_t)(k0 + r) * N + n0 + c];
    }
    __syncthreads();
#pragma unroll
    for (int i = 0; i < 4; i++) {
        const int idx = i * 256 + tid;
        const int n = idx >> 5, k = idx & 31;
        WT[(size_t)(n0 + n) * K + k0 + k] = f2bf(t[k][n]);
    }
}

// ---------------------------------------------------------------------------
// LayerNorm fp32 in -> bf16 out. One block per row (E=1024), 256 threads.
// ---------------------------------------------------------------------------
__global__ __launch_bounds__(256) void ln_bf16(const float* __restrict__ x,
                                               const float* __restrict__ g,
                                               const float* __restrict__ b,
                                               unsigned short* __restrict__ out) {
    const int row = blockIdx.x;
    const int tid = threadIdx.x;
    const float4 v = ((const float4*)(x + (size_t)row * E_))[tid];
    float s = v.x + v.y + v.z + v.w;
    float ss = v.x * v.x + v.y * v.y + v.z * v.z + v.w * v.w;
    for (int off = 32; off > 0; off >>= 1) {
        s += __shfl_down(s, off);
        ss += __shfl_down(ss, off);
    }
    __shared__ float rs[4], rss[4];
    const int wid = tid >> 6;
    if ((tid & 63) == 0) { rs[wid] = s; rss[wid] = ss; }
    __syncthreads();
    const float tot = rs[0] + rs[1] + rs[2] + rs[3];
    const float tot2 = rss[0] + rss[1] + rss[2] + rss[3];
    const float mean = tot * (1.0f / E_);
    const float var = tot2 * (1.0f / E_) - mean * mean;
    const float rstd = rsqrtf(var + 1e-5f);
    const float4 gv = ((const float4*)g)[tid];
    const float4 bv = ((const float4*)b)[tid];
    ushort4 o;
    o.x = f2bf((v.x - mean) * rstd * gv.x + bv.x);
    o.y = f2bf((v.y - mean) * rstd * gv.y + bv.y);
    o.z = f2bf((v.z - mean) * rstd * gv.z + bv.z);
    o.w = f2bf((v.w - mean) * rstd * gv.w + bv.w);
    ((ushort4*)(out + (size_t)row * E_))[tid] = o;
}

// stage one 16B chunk of a tile into LDS, source-side XOR swizzled
__device__ __forceinline__ void stage_half(const unsigned short* __restrict__ G,
                                           size_t rbase, int K, int k0,
                                           unsigned short* lds, int c) {
    const int r = c >> 3, s = c & 7;
    gload16(G + rbase + (size_t)r * K + k0 + ((s ^ (r & 7)) * 8),
            (char*)lds + c * 16);
}

// ---------------------------------------------------------------------------
// bf16 MFMA GEMM v4 (m201-geometry): C[M,N] = A[M,K] @ BT[N,K]^T (+epilogue)
// BM=256, BN={256,128}, BK=64, 512 thr = 8 waves.
//   BN=256: waves 2M x 4N, wave tile 128x64  (0.375 ds_read/MFMA)
//   BN=128: waves 4M x 2N, wave tile  64x64
// Double-buffered LDS (128/96 KB), stage(t+1) issued at top of iter t
// (full-tile compute cover), ONE vmcnt(0) + ONE barrier per K-tile; per-ks
// {12 ds_read -> 32 MFMA} with setprio so the 8 waves drift anti-phase and
// LDS reads overlap MFMA across waves.
// ---------------------------------------------------------------------------
template <int BN, int NWN, bool BIASF, bool RELU, bool RES, bool OUTBF16>
__global__ __launch_bounds__(512, 2) void gemm_v4(
    const unsigned short* __restrict__ A,    // [M][K] bf16
    const unsigned short* __restrict__ BT,   // [N][K] bf16
    const float* __restrict__ bias,
    const float* __restrict__ res,
    float* __restrict__ Cf,
    unsigned short* __restrict__ Cb,
    int M, int N, int K) {
    constexpr int NWM = 8 / NWN;       // 2 or 4
    constexpr int MW = 256 / NWM;      // wave M extent: 128 or 64
    constexpr int M_REP = MW / 16;     // 8 or 4
    constexpr int BPT = (BN * 64 / 8) / 512;  // B chunks per thread: 4 or 2

    __shared__ unsigned short As[2][256 * 64];  // 2 x 32 KB
    __shared__ unsigned short Bs[2][BN * 64];   // 2 x (32|16) KB

    const int tid = threadIdx.x;
    const int lane = tid & 63;
    const int w = tid >> 6;            // 0..7
    const int wm = w / NWN, wn = w % NWN;
    const int lm = lane & 15;
    const int kg = lane >> 4;

    // XCD swizzle (bijective: nwg % 8 == 0 for all grids used)
    const int gx = gridDim.x;
    const int nwg = gx * gridDim.y;
    const int lin = blockIdx.y * gx + blockIdx.x;
    const int cpx = nwg >> 3;
    const int swz = (lin & 7) * cpx + (lin >> 3);
    const int rowBase = (swz / gx) * 256, colBase = (swz % gx) * BN;

    const size_t rA = (size_t)rowBase * K;
    const size_t rB = (size_t)colBase * K;

    f32x4 acc[M_REP][4];
#pragma unroll
    for (int mt = 0; mt < M_REP; mt++)
#pragma unroll
        for (int nt = 0; nt < 4; nt++)
#pragma unroll
            for (int r = 0; r < 4; r++) acc[mt][nt][r] = 0.0f;

    const int nk = K >> 6;
    // prologue: stage tile 0
#pragma unroll
    for (int i = 0; i < 4; i++) stage_half(A, rA, K, 0, As[0], i * 512 + tid);
#pragma unroll
    for (int i = 0; i < BPT; i++) stage_half(BT, rB, K, 0, Bs[0], i * 512 + tid);
    asm volatile("s_waitcnt vmcnt(0)" ::: "memory");
    __builtin_amdgcn_s_barrier();
    __builtin_amdgcn_sched_barrier(0);

    for (int t = 0; t < nk; ++t) {
        const int cur = t & 1;
        // issue next tile's staging into the other buffer (covered by this
        // tile's entire compute)
        if (t + 1 < nk) {
#pragma unroll
            for (int i = 0; i < 4; i++)
                stage_half(A, rA, K, (t + 1) * 64, As[cur ^ 1], i * 512 + tid);
#pragma unroll
            for (int i = 0; i < BPT; i++)
                stage_half(BT, rB, K, (t + 1) * 64, Bs[cur ^ 1], i * 512 + tid);
        }
#pragma unroll
        for (int ks = 0; ks < 2; ++ks) {
            bf16x8 af[M_REP], bfr[4];
#pragma unroll
            for (int mt = 0; mt < M_REP; mt++) {
                const int r = wm * MW + mt * 16 + lm;
                af[mt] = *(const bf16x8*)(As[cur] + r * 64 +
                                          (((ks * 4 + kg) ^ (r & 7)) * 8));
            }
#pragma unroll
            for (int nt = 0; nt < 4; nt++) {
                const int r = wn * 64 + nt * 16 + lm;
                bfr[nt] = *(const bf16x8*)(Bs[cur] + r * 64 +
                                           (((ks * 4 + kg) ^ (r & 7)) * 8));
            }
            __builtin_amdgcn_s_setprio(1);
#pragma unroll
            for (int mt = 0; mt < M_REP; mt++)
#pragma unroll
                for (int nt = 0; nt < 4; nt++)
                    acc[mt][nt] = __builtin_amdgcn_mfma_f32_16x16x32_bf16(
                        af[mt], bfr[nt], acc[mt][nt], 0, 0, 0);
            __builtin_amdgcn_s_setprio(0);
        }
        if (t + 1 < nk) {
            asm volatile("s_waitcnt vmcnt(0)" ::: "memory");  // next tile ready
            __builtin_amdgcn_s_barrier();
            __builtin_amdgcn_sched_barrier(0);
        }
    }

    // epilogue: C/D layout col=lane&15, row=(lane>>4)*4+reg
#pragma unroll
    for (int mt = 0; mt < M_REP; mt++) {
#pragma unroll
        for (int nt = 0; nt < 4; nt++) {
            const int cg = colBase + wn * 64 + nt * 16 + lm;
#pragma unroll
            for (int r = 0; r < 4; r++) {
                const int rg = rowBase + wm * MW + mt * 16 + kg * 4 + r;
                float v = acc[mt][nt][r];
                if (BIASF) v += bias[cg];
                if (RELU) v = fmaxf(v, 0.0f);
                if (RES) v += res[(size_t)rg * N + cg];
                if (OUTBF16) Cb[(size_t)rg * N + cg] = f2bf(v);
                else Cf[(size_t)rg * N + cg] = v;
            }
        }
    }
}

// ---------------------------------------------------------------------------
// bf16 MFMA flash attention v3 (causal) — unchanged from round 6 (177 us
// characterized baseline; kept identical for clean attribution of the GEMM
// change this round).
// ---------------------------------------------------------------------------
__global__ __launch_bounds__(256) void attn_mfma3(const unsigned short* __restrict__ qkv,
                                                  unsigned short* __restrict__ out) {
    __shared__ unsigned short Ks[2][64 * 64];  // 2 x 8 KB, XOR-swizzled
    __shared__ unsigned short Vt[2][64 * 72];  // 2 x 9 KB, [d][kv] pitch 72

    const int tid = threadIdx.x;
    const int lane = tid & 63;
    const int w = tid >> 6;
    const int lm = lane & 15;
    const int kg = lane >> 4;
    const int qt = 15 - blockIdx.x;      // 0..15, descending dispatch
    const int bh = blockIdx.y;           // 0..63
    const int b = bh >> 4, h = bh & 15;
    const int bT = b * T_;
    const int q0w = qt * 128 + w * 32;
    const float K1 = 0.18033688011f;     // 0.125 * log2(e)

    // Q fragments [qg][d-chunk], hoisted
    bf16x8 qf[2][2];
#pragma unroll
    for (int qg = 0; qg < 2; qg++) {
        const size_t qo = (size_t)(bT + q0w + qg * 16 + lm) * QKV3_ + h * HS_;
#pragma unroll
        for (int dc = 0; dc < 2; dc++)
            qf[qg][dc] = *(const bf16x8*)(qkv + qo + dc * 32 + kg * 8);
    }

    f32x4 o[2][4];
#pragma unroll
    for (int qg = 0; qg < 2; qg++)
#pragma unroll
        for (int dt = 0; dt < 4; dt++)
#pragma unroll
            for (int r = 0; r < 4; r++) o[qg][dt][r] = 0.0f;
    float m2[2] = {-INFINITY, -INFINITY};
    float l[2] = {0.0f, 0.0f};

    // staging assignment
    const int rK = tid >> 3, chK = tid & 7;        // K: rows rK, rK+32; chunk chK
    const int sK = (chK ^ (rK & 7)) * 8;           // swizzled LDS slot (elems)
    const int rp = tid >> 3, chV = tid & 7;        // V: row pair 2rp,2rp+1
    const int vws = (2 * rp) ^ (chV << 2);         // swizzled kv-slot for V writes

    const size_t hK = E_ + h * HS_;
    const size_t hV = 2 * E_ + h * HS_;
    bf16x8 kA, kB, vA, vB;

#define LOADT(kvb)                                                                          \
    do {                                                                                    \
        kA = *(const bf16x8*)(qkv + (size_t)(bT + (kvb) + rK) * QKV3_ + hK + chK * 8);      \
        kB = *(const bf16x8*)(qkv + (size_t)(bT + (kvb) + rK + 32) * QKV3_ + hK + chK * 8); \
        vA = *(const bf16x8*)(qkv + (size_t)(bT + (kvb) + 2 * rp) * QKV3_ + hV + chV * 8);  \
        vB = *(const bf16x8*)(qkv + (size_t)(bT + (kvb) + 2 * rp + 1) * QKV3_ + hV + chV * 8); \
    } while (0)

    const int nt = 2 * (qt + 1);
    LOADT(0);
    for (int t = 0; t < nt; t++) {
        const int kvbase = t * 64;
        const int cb = t & 1;
        // write tile t (in regs) into buf cb
        *(bf16x8*)(Ks[cb] + rK * 64 + sK) = kA;
        *(bf16x8*)(Ks[cb] + (rK + 32) * 64 + sK) = kB;
#pragma unroll
        for (int i = 0; i < 8; i++) {
            const unsigned int pv = (unsigned int)(unsigned short)vA[i] |
                                    ((unsigned int)(unsigned short)vB[i] << 16);
            *(unsigned int*)(Vt[cb] + (chV * 8 + i) * 72 + vws) = pv;
        }
        if (t + 1 < nt) LOADT((t + 1) * 64);  // early-issue next tile (T14)
        asm volatile("s_waitcnt lgkmcnt(0)" ::: "memory");  // LDS writes visible
        __builtin_amdgcn_s_barrier();
        __builtin_amdgcn_sched_barrier(0);
        if (kvbase > q0w + 31) continue;  // wave fully masked (uniform)

        // K fragments (conflict-free swizzled b128)
        bf16x8 af[4][2];
#pragma unroll
        for (int g = 0; g < 4; g++)
#pragma unroll
            for (int dc = 0; dc < 2; dc++)
                af[g][dc] = *(const bf16x8*)(Ks[cb] + (g * 16 + lm) * 64 +
                                             (((dc * 4 + kg) ^ (lm & 7)) * 8));

        bf16x8 pa[2][2];
#pragma unroll
        for (int qg = 0; qg < 2; qg++) {
            f32x4 z = {0.0f, 0.0f, 0.0f, 0.0f};
            f32x4 s[4];
#pragma unroll
            for (int g = 0; g < 4; g++) {
                s[g] = __builtin_amdgcn_mfma_f32_16x16x32_bf16(af[g][0], qf[qg][0], z, 0, 0, 0);
                s[g] = __builtin_amdgcn_mfma_f32_16x16x32_bf16(af[g][1], qf[qg][1], s[g], 0, 0, 0);
            }
            const int qrow = q0w + qg * 16 + lm;
            float sv[16];
#pragma unroll
            for (int g = 0; g < 4; g++)
#pragma unroll
                for (int r = 0; r < 4; r++) sv[g * 4 + r] = s[g][r];
            if (kvbase + 63 > q0w + qg * 16) {  // diagonal tile: causal mask
#pragma unroll
                for (int g = 0; g < 4; g++)
#pragma unroll
                    for (int r = 0; r < 4; r++) {
                        const int kv = kvbase + g * 16 + kg * 4 + r;
                        if (kv > qrow) sv[g * 4 + r] = -INFINITY;
                    }
            }
            // depth-4 max tree
            const float mx = fmaxf(
                fmaxf(fmaxf(fmaxf(sv[0], sv[1]), fmaxf(sv[2], sv[3])),
                      fmaxf(fmaxf(sv[4], sv[5]), fmaxf(sv[6], sv[7]))),
                fmaxf(fmaxf(fmaxf(sv[8], sv[9]), fmaxf(sv[10], sv[11])),
                      fmaxf(fmaxf(sv[12], sv[13]), fmaxf(sv[14], sv[15]))));
            float mxw = fmaxf(mx, __shfl_xor(mx, 16));
            mxw = fmaxf(mxw, __shfl_xor(mxw, 32));
            const float mx2 = mxw * K1;
            // defer-max: rescale only when max grew beyond threshold (uniform)
            if (!__all(m2[qg] > -1e30f && mx2 <= m2[qg] + 11.5f)) {
                const float m2new = fmaxf(m2[qg], mx2);
                const float alpha = exp2f(m2[qg] - m2new);
#pragma unroll
                for (int r = 0; r < 4; r++) {
                    const float ar = __shfl(alpha, kg * 4 + r);
#pragma unroll
                    for (int dt = 0; dt < 4; dt++) o[qg][dt][r] *= ar;
                }
                l[qg] *= alpha;
                m2[qg] = m2new;
            }
            float p[16];
#pragma unroll
            for (int j = 0; j < 16; j++) p[j] = exp2f(fmaf(sv[j], K1, -m2[qg]));
            // depth-4 sum tree
            float ls = (((p[0] + p[1]) + (p[2] + p[3])) + ((p[4] + p[5]) + (p[6] + p[7]))) +
                       (((p[8] + p[9]) + (p[10] + p[11])) + ((p[12] + p[13]) + (p[14] + p[15])));
            ls += __shfl_xor(ls, 16);
            ls += __shfl_xor(ls, 32);
            l[qg] += ls;
#pragma unroll
            for (int j = 0; j < 8; j++) {
                ((unsigned short*)&pa[qg][0])[j] = f2bf(p[j]);
                ((unsigned short*)&pa[qg][1])[j] = f2bf(p[8 + j]);
            }
        }

        // PV: vf fragments (2x b64 each, de-swizzled via row-octet XOR), shared
        // by both q-groups
#pragma unroll
        for (int dt = 0; dt < 4; dt++) {
            const int drow = dt * 16 + lm;
            const unsigned short* vrow = Vt[cb] + drow * 72;
            const int xo = (kg * 4) ^ (((drow >> 3) & 7) << 2);
#pragma unroll
            for (int c = 0; c < 2; c++) {
                const bf16x4 lo = *(const bf16x4*)(vrow + c * 32 + xo);
                const bf16x4 hi = *(const bf16x4*)(vrow + c * 32 + (xo ^ 16));
                const bf16x8 vf = __builtin_shufflevector(lo, hi, 0, 1, 2, 3, 4, 5, 6, 7);
                o[0][dt] = __builtin_amdgcn_mfma_f32_16x16x32_bf16(pa[0][c], vf, o[0][dt], 0, 0, 0);
                o[1][dt] = __builtin_amdgcn_mfma_f32_16x16x32_bf16(pa[1][c], vf, o[1][dt], 0, 0, 0);
            }
        }
    }
#undef LOADT

    // epilogue: out row q = kg*4+r (per qg), col d = dt*16+lm
#pragma unroll
    for (int qg = 0; qg < 2; qg++)
#pragma unroll
        for (int r = 0; r < 4; r++) {
            const float li = 1.0f / __shfl(l[qg], kg * 4 + r);
            const size_t ro = (size_t)(bT + q0w + qg * 16 + kg * 4 + r) * E_ + h * HS_;
#pragma unroll
            for (int dt = 0; dt < 4; dt++)
                out[ro + dt * 16 + lm] = f2bf(o[qg][dt][r] * li);
        }
}

// ---------------------------------------------------------------------------
// Workspace layout (bytes): peak ~120 MB.
// ---------------------------------------------------------------------------
extern "C" void kernel_launch(void* const* d_in, const int* in_sizes, int n_in,
                              void* d_out, int out_size, void* d_ws, size_t ws_size,
                              hipStream_t stream) {
    const float* x           = (const float*)d_in[0];
    const float* qkv_w       = (const float*)d_in[1];
    const float* attn_proj_w = (const float*)d_in[2];
    const float* attn_proj_b = (const float*)d_in[3];
    const float* ln1_g       = (const float*)d_in[4];
    const float* ln1_b       = (const float*)d_in[5];
    const float* ln2_g       = (const float*)d_in[6];
    const float* ln2_b       = (const float*)d_in[7];
    const float* ff_w1       = (const float*)d_in[8];
    const float* ff_b1       = (const float*)d_in[9];
    const float* ff_w2       = (const float*)d_in[10];
    const float* ff_b2       = (const float*)d_in[11];
    float* out = (float*)d_out;
    char* wsb = (char*)d_ws;

    unsigned short* wqkvT  = (unsigned short*)(wsb + 0);
    unsigned short* wprojT = (unsigned short*)(wsb + 6291456);
    unsigned short* wff1T  = (unsigned short*)(wsb + 8388608);
    unsigned short* wff2T  = (unsigned short*)(wsb + 16777216);
    unsigned short* hbuf   = (unsigned short*)(wsb + 25165824);
    unsigned short* attnb  = (unsigned short*)(wsb + 41943040);
    unsigned short* qkvb   = (unsigned short*)(wsb + 58720256);
    unsigned short* ff1b   = qkvb;  // reuse (qkv dead after attention)

    // weight transposes (W[K][N] -> WT[N][K] bf16)
    wT_bf16<<<dim3(QKV3_ / 32, E_ / 32), 256, 0, stream>>>(qkv_w, wqkvT, E_, QKV3_);
    wT_bf16<<<dim3(E_ / 32, E_ / 32), 256, 0, stream>>>(attn_proj_w, wprojT, E_, E_);
    wT_bf16<<<dim3(FF_ / 32, E_ / 32), 256, 0, stream>>>(ff_w1, wff1T, E_, FF_);
    wT_bf16<<<dim3(E_ / 32, FF_ / 32), 256, 0, stream>>>(ff_w2, wff2T, FF_, E_);

    // 1. h = LN1(x) -> bf16
    ln_bf16<<<M_, 256, 0, stream>>>(x, ln1_g, ln1_b, hbuf);
    // 2. qkv = h @ qkv_w -> bf16   (grid 12x32 = 384 blocks, BN=256)
    gemm_v4<256, 4, false, false, false, true><<<dim3(QKV3_ / 256, M_ / 256), 512, 0, stream>>>(
        hbuf, wqkvT, nullptr, nullptr, nullptr, qkvb, M_, QKV3_, E_);
    // 3. attn = causal_flash(qkv) -> bf16
    attn_mfma3<<<dim3(T_ / 128, B_ * H_), 256, 0, stream>>>(qkvb, attnb);
    // 4. x1 = x + attn @ proj_w + proj_b -> d_out (fp32)  (grid 8x32 = 256, BN=128)
    gemm_v4<128, 2, true, false, true, false><<<dim3(E_ / 128, M_ / 256), 512, 0, stream>>>(
        attnb, wprojT, attn_proj_b, x, out, nullptr, M_, E_, E_);
    // 5. h2 = LN2(x1) -> bf16
    ln_bf16<<<M_, 256, 0, stream>>>(out, ln2_g, ln2_b, hbuf);
    // 6. ff = relu(h2 @ ff_w1 + b1) -> bf16   (grid 16x32 = 512, BN=256)
    gemm_v4<256, 4, true, true, false, true><<<dim3(FF_ / 256, M_ / 256), 512, 0, stream>>>(
        hbuf, wff1T, ff_b1, nullptr, nullptr, ff1b, M_, FF_, E_);
    // 7. out = x1 + ff @ ff_w2 + b2 -> d_out (fp32, in-place)  (grid 8x32 = 256, BN=128)
    gemm_v4<128, 2, true, false, true, false><<<dim3(E_ / 128, M_ / 256), 512, 0, stream>>>(
        ff1b, wff2T, ff_b2, out, out, nullptr, M_, E_, FF_);
    (void)ws_size; (void)in_sizes; (void)n_in; (void)out_size;
}